// Round 5
// baseline (673.424 us; speedup 1.0000x reference)
//
#include <hip/hip_runtime.h>
#include <hip/hip_bf16.h>
#include <math.h>

// NT-Xent (CLIP) loss, N=16384 D=256 fp32 in, 3 fp32 out.
// loss_vu = mean_i( log(sum_j exp(sim_ij)) - sim_ii ), sim = (v̂·û^T)/T
// Logits bounded by 1/T=14.29 -> no max subtraction needed for exp stability.
//
// R5: revert to R2 VGPR staging (global_load_lds regressed: it pins the LDS
//     write to the load, defeating cross-barrier load hoisting on our short
//     4-iter K loop). Add XCD-aware block swizzle (16-i-tile slab per XCD,
//     j-major within slab -> B strip L2-resident across 16 i-tiles, A slab
//     1 MiB L2-resident) + exp2f with folded scale.

#define D_DIM 256
#define BM 128
#define BN 128
#define BK 64

constexpr float INV_T = 1.0f / 0.07f;
constexpr float EXP2_SCALE = 1.44269504088896f / 0.07f;  // log2(e)/T

typedef __bf16 bf16x8 __attribute__((ext_vector_type(8)));
typedef float f32x4 __attribute__((ext_vector_type(4)));

// ---------------------------------------------------------------------------
// Kernel 1: L2-normalize (fp32 -> bf16), one WAVE per row (4 rows/block).
//           Writes per-row diag contribution v̂_i·û_i to diagarr (no atomic).
//           Blocks 0..127 also zero rowsum/colsum; block 128 zeros acc3.
// ---------------------------------------------------------------------------
__global__ __launch_bounds__(256) void normalize_kernel(
    const float* __restrict__ img, const float* __restrict__ txt,
    __hip_bfloat16* __restrict__ Vb, __hip_bfloat16* __restrict__ Ub,
    float* __restrict__ diagarr, float* __restrict__ zero_region,
    float* __restrict__ acc3) {
  if (blockIdx.x < 128)
    zero_region[blockIdx.x * 256 + threadIdx.x] = 0.0f;
  else if (blockIdx.x == 128 && threadIdx.x < 4)
    acc3[threadIdx.x] = 0.0f;

  const int wave = threadIdx.x >> 6;
  const int lane = threadIdx.x & 63;
  const int row = blockIdx.x * 4 + wave;
  const size_t base = (size_t)row * D_DIM + lane * 4;

  const float4 iv = *reinterpret_cast<const float4*>(&img[base]);
  const float4 tv = *reinterpret_cast<const float4*>(&txt[base]);

  float a = iv.x * iv.x + iv.y * iv.y + iv.z * iv.z + iv.w * iv.w;
  float b = tv.x * tv.x + tv.y * tv.y + tv.z * tv.z + tv.w * tv.w;
#pragma unroll
  for (int off = 1; off < 64; off <<= 1) {
    a += __shfl_xor(a, off, 64);
    b += __shfl_xor(b, off, 64);
  }
  const float si = 1.0f / fmaxf(sqrtf(a), 1e-8f);
  const float st = 1.0f / fmaxf(sqrtf(b), 1e-8f);
  const float4 v = {iv.x * si, iv.y * si, iv.z * si, iv.w * si};
  const float4 u = {tv.x * st, tv.y * st, tv.z * st, tv.w * st};

  __hip_bfloat16 vb4[4] = {__float2bfloat16(v.x), __float2bfloat16(v.y),
                           __float2bfloat16(v.z), __float2bfloat16(v.w)};
  __hip_bfloat16 ub4[4] = {__float2bfloat16(u.x), __float2bfloat16(u.y),
                           __float2bfloat16(u.z), __float2bfloat16(u.w)};
  *reinterpret_cast<uint2*>(&Vb[base]) = *reinterpret_cast<uint2*>(vb4);
  *reinterpret_cast<uint2*>(&Ub[base]) = *reinterpret_cast<uint2*>(ub4);

  float d = v.x * u.x + v.y * u.y + v.z * u.z + v.w * u.w;
#pragma unroll
  for (int off = 1; off < 64; off <<= 1) d += __shfl_xor(d, off, 64);
  if (lane == 0) diagarr[row] = d;
}

// ---------------------------------------------------------------------------
// Kernel 2: tiled bf16 MFMA GEMM over sim = V·U^T, online exp-sum per row
//           and per column. 128x128 tile/block, 4 waves of 64x64.
// VGPR staging (R2 structure): loads for tile kk+1 are hoistable above the
// compute of tile kk by the compiler (only ds_write waits at the barrier).
// LDS XOR-swizzled: 16B chunk c8 of row r stored at chunk (c8 ^ (r&7));
// staging writes and frag reads both <=2 lanes/bank (R2: conflicts == 0).
// XCD swizzle: bid&7 selects a 16-i-tile slab; within a slab, j-major order
// gives B-strip reuse (16 consecutive blocks share one 64 KB B strip) and
// keeps the 1 MiB A slab L2-resident.
// A-frag (16x16x32): A[m=lane&15][k=quad*8+j]; B symmetric (U row-major).
// C/D: col=lane&15, row=quad*4+reg (m89/m91-verified).
// ---------------------------------------------------------------------------
__global__ __launch_bounds__(256, 5) void gemm_lse_kernel(
    const __hip_bfloat16* __restrict__ V, const __hip_bfloat16* __restrict__ U,
    float* __restrict__ rowsum, float* __restrict__ colsum) {
  __shared__ __align__(16) unsigned short As[BM * BK];  // 16 KB
  __shared__ __align__(16) unsigned short Bs[BN * BK];  // 16 KB

  const int tid = threadIdx.x;
  const int lane = tid & 63;
  const int wave = tid >> 6;
  const int wm = wave >> 1;   // wave row (0..1)
  const int wn = wave & 1;    // wave col (0..1)
  const int quad = lane >> 4;
  const int l15 = lane & 15;
  const int sw = l15 & 7;     // read-swizzle factor (= frag row & 7)

  // XCD-aware tile mapping (bijective on 128x128 tiles):
  //   xcd = bid&7 -> i-slab [xcd*16, xcd*16+16); s=bid>>3: j = s>>4 (outer),
  //   i = slab + (s&15) (inner).
  const int bid = blockIdx.x;
  const int jt = (bid >> 3) >> 4;                  // 0..127
  const int it = (bid & 7) * 16 + ((bid >> 3) & 15);  // 0..127
  const int ibase = it * BM;
  const int jbase = jt * BN;

  f32x4 acc[4][4] = {};

  for (int kk = 0; kk < D_DIM; kk += BK) {
    // Stage A and B tiles: 1024 x 16B chunks each; 4 chunks/thread each.
#pragma unroll
    for (int q = 0; q < 4; ++q) {
      const int chunk = q * 256 + tid;  // [0,1024)
      const int row = chunk >> 3;       // 8 x 16B per 64-col row
      const int c8 = chunk & 7;
      const int dst = row * BK + (((c8 ^ (row & 7))) << 3);  // swizzled
      const uint4 va = *reinterpret_cast<const uint4*>(
          &V[(size_t)(ibase + row) * D_DIM + kk + c8 * 8]);
      const uint4 vb = *reinterpret_cast<const uint4*>(
          &U[(size_t)(jbase + row) * D_DIM + kk + c8 * 8]);
      *reinterpret_cast<uint4*>(&As[dst]) = va;
      *reinterpret_cast<uint4*>(&Bs[dst]) = vb;
    }
    __syncthreads();

#pragma unroll
    for (int ks = 0; ks < BK; ks += 32) {
      const int c8a = (ks >> 3) + quad;          // logical 16B chunk
      const int pc = ((c8a ^ sw) << 3);          // swizzled short offset
      bf16x8 af[4], bfr[4];
#pragma unroll
      for (int mi = 0; mi < 4; ++mi)
        af[mi] = *reinterpret_cast<const bf16x8*>(
            &As[(wm * 64 + mi * 16 + l15) * BK + pc]);
#pragma unroll
      for (int ni = 0; ni < 4; ++ni)
        bfr[ni] = *reinterpret_cast<const bf16x8*>(
            &Bs[(wn * 64 + ni * 16 + l15) * BK + pc]);
#pragma unroll
      for (int mi = 0; mi < 4; ++mi)
#pragma unroll
        for (int ni = 0; ni < 4; ++ni)
          acc[mi][ni] = __builtin_amdgcn_mfma_f32_16x16x32_bf16(
              af[mi], bfr[ni], acc[mi][ni], 0, 0, 0);
    }
    __syncthreads();
  }

  // ---- epilogue: exp + row/col reduction ----
  // acc[mi][ni][r]: row = wm*64+mi*16+quad*4+r, col = wn*64+ni*16+l15.
  // exp(s/T) = exp2(s * log2e/T) -> single mul + native v_exp_f32.
#pragma unroll
  for (int mi = 0; mi < 4; ++mi)
#pragma unroll
    for (int ni = 0; ni < 4; ++ni)
#pragma unroll
      for (int r = 0; r < 4; ++r)
        acc[mi][ni][r] = exp2f(acc[mi][ni][r] * EXP2_SCALE);

  // Reuse As as fp32 scratch: rowbuf[128], colbuf[128].
  float* rowbuf = reinterpret_cast<float*>(As);
  float* colbuf = rowbuf + BM;
  reinterpret_cast<float*>(As)[tid] = 0.0f;  // zero 256 floats
  __syncthreads();

  // Row sums: reduce across 16 cols, two wn halves meet in LDS.
#pragma unroll
  for (int mi = 0; mi < 4; ++mi) {
#pragma unroll
    for (int r = 0; r < 4; ++r) {
      float rs = acc[mi][0][r] + acc[mi][1][r] + acc[mi][2][r] + acc[mi][3][r];
      rs += __shfl_xor(rs, 1, 64);
      rs += __shfl_xor(rs, 2, 64);
      rs += __shfl_xor(rs, 4, 64);
      rs += __shfl_xor(rs, 8, 64);
      if (l15 == 0)
        atomicAdd(&rowbuf[wm * 64 + mi * 16 + quad * 4 + r], rs);
    }
  }
  // Col sums: reduce across 16 rows (quads), two wm halves meet in LDS.
#pragma unroll
  for (int ni = 0; ni < 4; ++ni) {
    float cs = 0.0f;
#pragma unroll
    for (int mi = 0; mi < 4; ++mi)
      cs += acc[mi][ni][0] + acc[mi][ni][1] + acc[mi][ni][2] + acc[mi][ni][3];
    cs += __shfl_xor(cs, 16, 64);
    cs += __shfl_xor(cs, 32, 64);
    if (lane < 16)
      atomicAdd(&colbuf[wn * 64 + ni * 16 + l15], cs);
  }
  __syncthreads();

  if (tid < BM)
    atomicAdd(&rowsum[ibase + tid], rowbuf[tid]);
  else
    atomicAdd(&colsum[jbase + tid - BM], colbuf[tid - BM]);
}

// ---------------------------------------------------------------------------
// Kernel 3a: parallel partial finalize — 64 blocks; block-reduce; one
//            atomicAdd per block into acc3[3].
// ---------------------------------------------------------------------------
__global__ __launch_bounds__(256) void finalize_partial(
    const float* __restrict__ rowsum, const float* __restrict__ colsum,
    const float* __restrict__ diagarr, float* __restrict__ acc3) {
  const int idx = blockIdx.x * 256 + threadIdx.x;
  float sr = logf(rowsum[idx]);
  float sc = logf(colsum[idx]);
  float sd = diagarr[idx];
#pragma unroll
  for (int off = 1; off < 64; off <<= 1) {
    sr += __shfl_xor(sr, off, 64);
    sc += __shfl_xor(sc, off, 64);
    sd += __shfl_xor(sd, off, 64);
  }
  __shared__ float sh[12];
  const int w = threadIdx.x >> 6, lane = threadIdx.x & 63;
  if (lane == 0) { sh[w] = sr; sh[4 + w] = sc; sh[8 + w] = sd; }
  __syncthreads();
  if (threadIdx.x == 0) {
    atomicAdd(&acc3[0], sh[0] + sh[1] + sh[2] + sh[3]);
    atomicAdd(&acc3[1], sh[4] + sh[5] + sh[6] + sh[7]);
    atomicAdd(&acc3[2], sh[8] + sh[9] + sh[10] + sh[11]);
  }
}

// ---------------------------------------------------------------------------
// Kernel 3b: combine.
// ---------------------------------------------------------------------------
__global__ __launch_bounds__(64) void finalize_combine(
    const float* __restrict__ acc3, float* __restrict__ out, int n) {
  if (threadIdx.x == 0) {
    const float invN = 1.0f / (float)n;
    const float dm = acc3[2] * INV_T * invN;   // mean diag logit
    const float lvu = acc3[0] * invN - dm;
    const float luv = acc3[1] * invN - dm;
    out[0] = 0.5f * lvu + 0.5f * luv;  // WEIGHT = 0.5
    out[1] = lvu;
    out[2] = luv;
  }
}

extern "C" void kernel_launch(void* const* d_in, const int* in_sizes, int n_in,
                              void* d_out, int out_size, void* d_ws, size_t ws_size,
                              hipStream_t stream) {
  const float* img = (const float*)d_in[0];
  const float* txt = (const float*)d_in[1];
  float* out = (float*)d_out;
  const int N = in_sizes[0] / D_DIM;  // 16384

  char* ws = (char*)d_ws;
  __hip_bfloat16* Vb = (__hip_bfloat16*)ws;
  __hip_bfloat16* Ub = (__hip_bfloat16*)(ws + (size_t)N * D_DIM * 2);
  float* rowsum = (float*)(ws + (size_t)N * D_DIM * 4);
  float* colsum = rowsum + N;
  float* diagarr = colsum + N;
  float* acc3 = diagarr + N;

  normalize_kernel<<<N / 4, 256, 0, stream>>>(img, txt, Vb, Ub, diagarr,
                                              rowsum, acc3);

  const int nblocks = (N / BM) * (N / BN);  // 16384, 1-D grid for swizzle
  gemm_lse_kernel<<<nblocks, 256, 0, stream>>>(Vb, Ub, rowsum, colsum);

  finalize_partial<<<N / 256, 256, 0, stream>>>(rowsum, colsum, diagarr, acc3);
  finalize_combine<<<1, 64, 0, stream>>>(acc3, out, N);
}

// Round 6
// 347.450 us; speedup vs baseline: 1.9382x; 1.9382x over previous
//
#include <hip/hip_runtime.h>
#include <hip/hip_bf16.h>
#include <math.h>

// NT-Xent (CLIP) loss, N=16384 D=256 fp32 in, 3 fp32 out.
// loss_vu = mean_i( log(sum_j exp(sim_ij)) - sim_ii ), sim = (v̂·û^T)/T
// Logits bounded by 1/T=14.29 -> no max subtraction needed for exp stability.
//
// R6: R5 minus the fatal __launch_bounds__(256,5) (it forced VGPR cap ~102
//     incl. 64 acc regs in the unified file -> accumulator spill -> 1.77 GB
//     scratch writes -> HBM-bound at 620 us). Plain 256 restores R2's
//     register budget. Keeps XCD swizzle + exp2f from R5.

#define D_DIM 256
#define BM 128
#define BN 128
#define BK 64

constexpr float INV_T = 1.0f / 0.07f;
constexpr float EXP2_SCALE = 1.44269504088896f / 0.07f;  // log2(e)/T

typedef __bf16 bf16x8 __attribute__((ext_vector_type(8)));
typedef float f32x4 __attribute__((ext_vector_type(4)));

// ---------------------------------------------------------------------------
// Kernel 1: L2-normalize (fp32 -> bf16), one WAVE per row (4 rows/block).
//           Writes per-row diag contribution v̂_i·û_i to diagarr (no atomic).
//           Blocks 0..127 also zero rowsum/colsum; block 128 zeros acc3.
// ---------------------------------------------------------------------------
__global__ __launch_bounds__(256) void normalize_kernel(
    const float* __restrict__ img, const float* __restrict__ txt,
    __hip_bfloat16* __restrict__ Vb, __hip_bfloat16* __restrict__ Ub,
    float* __restrict__ diagarr, float* __restrict__ zero_region,
    float* __restrict__ acc3) {
  if (blockIdx.x < 128)
    zero_region[blockIdx.x * 256 + threadIdx.x] = 0.0f;
  else if (blockIdx.x == 128 && threadIdx.x < 4)
    acc3[threadIdx.x] = 0.0f;

  const int wave = threadIdx.x >> 6;
  const int lane = threadIdx.x & 63;
  const int row = blockIdx.x * 4 + wave;
  const size_t base = (size_t)row * D_DIM + lane * 4;

  const float4 iv = *reinterpret_cast<const float4*>(&img[base]);
  const float4 tv = *reinterpret_cast<const float4*>(&txt[base]);

  float a = iv.x * iv.x + iv.y * iv.y + iv.z * iv.z + iv.w * iv.w;
  float b = tv.x * tv.x + tv.y * tv.y + tv.z * tv.z + tv.w * tv.w;
#pragma unroll
  for (int off = 1; off < 64; off <<= 1) {
    a += __shfl_xor(a, off, 64);
    b += __shfl_xor(b, off, 64);
  }
  const float si = 1.0f / fmaxf(sqrtf(a), 1e-8f);
  const float st = 1.0f / fmaxf(sqrtf(b), 1e-8f);
  const float4 v = {iv.x * si, iv.y * si, iv.z * si, iv.w * si};
  const float4 u = {tv.x * st, tv.y * st, tv.z * st, tv.w * st};

  __hip_bfloat16 vb4[4] = {__float2bfloat16(v.x), __float2bfloat16(v.y),
                           __float2bfloat16(v.z), __float2bfloat16(v.w)};
  __hip_bfloat16 ub4[4] = {__float2bfloat16(u.x), __float2bfloat16(u.y),
                           __float2bfloat16(u.z), __float2bfloat16(u.w)};
  *reinterpret_cast<uint2*>(&Vb[base]) = *reinterpret_cast<uint2*>(vb4);
  *reinterpret_cast<uint2*>(&Ub[base]) = *reinterpret_cast<uint2*>(ub4);

  float d = v.x * u.x + v.y * u.y + v.z * u.z + v.w * u.w;
#pragma unroll
  for (int off = 1; off < 64; off <<= 1) d += __shfl_xor(d, off, 64);
  if (lane == 0) diagarr[row] = d;
}

// ---------------------------------------------------------------------------
// Kernel 2: tiled bf16 MFMA GEMM over sim = V·U^T, online exp-sum per row
//           and per column. 128x128 tile/block, 4 waves of 64x64.
// VGPR staging (R2 structure): loads for tile kk+1 are hoistable above the
// compute of tile kk by the compiler (only ds_write waits at the barrier).
// LDS XOR-swizzled: 16B chunk c8 of row r stored at chunk (c8 ^ (r&7));
// staging writes and frag reads both <=2 lanes/bank (R2: conflicts == 0).
// XCD swizzle: bid&7 selects a 16-i-tile slab; within a slab, j-major order
// gives B-strip reuse and keeps the 1 MiB A slab L2-resident.
// A-frag (16x16x32): A[m=lane&15][k=quad*8+j]; B symmetric (U row-major).
// C/D: col=lane&15, row=quad*4+reg (m89/m91-verified).
// NOTE: no min-waves launch bound — 64 acc regs + ~84 VGPRs in the unified
// file put the natural point at 3 waves/SIMD; forcing 5 spills acc (R5).
// ---------------------------------------------------------------------------
__global__ __launch_bounds__(256) void gemm_lse_kernel(
    const __hip_bfloat16* __restrict__ V, const __hip_bfloat16* __restrict__ U,
    float* __restrict__ rowsum, float* __restrict__ colsum) {
  __shared__ __align__(16) unsigned short As[BM * BK];  // 16 KB
  __shared__ __align__(16) unsigned short Bs[BN * BK];  // 16 KB

  const int tid = threadIdx.x;
  const int lane = tid & 63;
  const int wave = tid >> 6;
  const int wm = wave >> 1;   // wave row (0..1)
  const int wn = wave & 1;    // wave col (0..1)
  const int quad = lane >> 4;
  const int l15 = lane & 15;
  const int sw = l15 & 7;     // read-swizzle factor (= frag row & 7)

  // XCD-aware tile mapping (bijective on 128x128 tiles):
  const int bid = blockIdx.x;
  const int jt = (bid >> 3) >> 4;                     // 0..127
  const int it = (bid & 7) * 16 + ((bid >> 3) & 15);  // 0..127
  const int ibase = it * BM;
  const int jbase = jt * BN;

  f32x4 acc[4][4] = {};

  for (int kk = 0; kk < D_DIM; kk += BK) {
    // Stage A and B tiles: 1024 x 16B chunks each; 4 chunks/thread each.
#pragma unroll
    for (int q = 0; q < 4; ++q) {
      const int chunk = q * 256 + tid;  // [0,1024)
      const int row = chunk >> 3;       // 8 x 16B per 64-col row
      const int c8 = chunk & 7;
      const int dst = row * BK + (((c8 ^ (row & 7))) << 3);  // swizzled
      const uint4 va = *reinterpret_cast<const uint4*>(
          &V[(size_t)(ibase + row) * D_DIM + kk + c8 * 8]);
      const uint4 vb = *reinterpret_cast<const uint4*>(
          &U[(size_t)(jbase + row) * D_DIM + kk + c8 * 8]);
      *reinterpret_cast<uint4*>(&As[dst]) = va;
      *reinterpret_cast<uint4*>(&Bs[dst]) = vb;
    }
    __syncthreads();

#pragma unroll
    for (int ks = 0; ks < BK; ks += 32) {
      const int c8a = (ks >> 3) + quad;          // logical 16B chunk
      const int pc = ((c8a ^ sw) << 3);          // swizzled short offset
      bf16x8 af[4], bfr[4];
#pragma unroll
      for (int mi = 0; mi < 4; ++mi)
        af[mi] = *reinterpret_cast<const bf16x8*>(
            &As[(wm * 64 + mi * 16 + l15) * BK + pc]);
#pragma unroll
      for (int ni = 0; ni < 4; ++ni)
        bfr[ni] = *reinterpret_cast<const bf16x8*>(
            &Bs[(wn * 64 + ni * 16 + l15) * BK + pc]);
#pragma unroll
      for (int mi = 0; mi < 4; ++mi)
#pragma unroll
        for (int ni = 0; ni < 4; ++ni)
          acc[mi][ni] = __builtin_amdgcn_mfma_f32_16x16x32_bf16(
              af[mi], bfr[ni], acc[mi][ni], 0, 0, 0);
    }
    __syncthreads();
  }

  // ---- epilogue: exp + row/col reduction ----
  // acc[mi][ni][r]: row = wm*64+mi*16+quad*4+r, col = wn*64+ni*16+l15.
#pragma unroll
  for (int mi = 0; mi < 4; ++mi)
#pragma unroll
    for (int ni = 0; ni < 4; ++ni)
#pragma unroll
      for (int r = 0; r < 4; ++r)
        acc[mi][ni][r] = exp2f(acc[mi][ni][r] * EXP2_SCALE);

  // Reuse As as fp32 scratch: rowbuf[128], colbuf[128].
  float* rowbuf = reinterpret_cast<float*>(As);
  float* colbuf = rowbuf + BM;
  reinterpret_cast<float*>(As)[tid] = 0.0f;  // zero 256 floats
  __syncthreads();

  // Row sums: reduce across 16 cols, two wn halves meet in LDS.
#pragma unroll
  for (int mi = 0; mi < 4; ++mi) {
#pragma unroll
    for (int r = 0; r < 4; ++r) {
      float rs = acc[mi][0][r] + acc[mi][1][r] + acc[mi][2][r] + acc[mi][3][r];
      rs += __shfl_xor(rs, 1, 64);
      rs += __shfl_xor(rs, 2, 64);
      rs += __shfl_xor(rs, 4, 64);
      rs += __shfl_xor(rs, 8, 64);
      if (l15 == 0)
        atomicAdd(&rowbuf[wm * 64 + mi * 16 + quad * 4 + r], rs);
    }
  }
  // Col sums: reduce across 16 rows (quads), two wm halves meet in LDS.
#pragma unroll
  for (int ni = 0; ni < 4; ++ni) {
    float cs = 0.0f;
#pragma unroll
    for (int mi = 0; mi < 4; ++mi)
      cs += acc[mi][ni][0] + acc[mi][ni][1] + acc[mi][ni][2] + acc[mi][ni][3];
    cs += __shfl_xor(cs, 16, 64);
    cs += __shfl_xor(cs, 32, 64);
    if (lane < 16)
      atomicAdd(&colbuf[wn * 64 + ni * 16 + l15], cs);
  }
  __syncthreads();

  if (tid < BM)
    atomicAdd(&rowsum[ibase + tid], rowbuf[tid]);
  else
    atomicAdd(&colsum[jbase + tid - BM], colbuf[tid - BM]);
}

// ---------------------------------------------------------------------------
// Kernel 3a: parallel partial finalize — 64 blocks; block-reduce; one
//            atomicAdd per block into acc3[3].
// ---------------------------------------------------------------------------
__global__ __launch_bounds__(256) void finalize_partial(
    const float* __restrict__ rowsum, const float* __restrict__ colsum,
    const float* __restrict__ diagarr, float* __restrict__ acc3) {
  const int idx = blockIdx.x * 256 + threadIdx.x;
  float sr = logf(rowsum[idx]);
  float sc = logf(colsum[idx]);
  float sd = diagarr[idx];
#pragma unroll
  for (int off = 1; off < 64; off <<= 1) {
    sr += __shfl_xor(sr, off, 64);
    sc += __shfl_xor(sc, off, 64);
    sd += __shfl_xor(sd, off, 64);
  }
  __shared__ float sh[12];
  const int w = threadIdx.x >> 6, lane = threadIdx.x & 63;
  if (lane == 0) { sh[w] = sr; sh[4 + w] = sc; sh[8 + w] = sd; }
  __syncthreads();
  if (threadIdx.x == 0) {
    atomicAdd(&acc3[0], sh[0] + sh[1] + sh[2] + sh[3]);
    atomicAdd(&acc3[1], sh[4] + sh[5] + sh[6] + sh[7]);
    atomicAdd(&acc3[2], sh[8] + sh[9] + sh[10] + sh[11]);
  }
}

// ---------------------------------------------------------------------------
// Kernel 3b: combine.
// ---------------------------------------------------------------------------
__global__ __launch_bounds__(64) void finalize_combine(
    const float* __restrict__ acc3, float* __restrict__ out, int n) {
  if (threadIdx.x == 0) {
    const float invN = 1.0f / (float)n;
    const float dm = acc3[2] * INV_T * invN;   // mean diag logit
    const float lvu = acc3[0] * invN - dm;
    const float luv = acc3[1] * invN - dm;
    out[0] = 0.5f * lvu + 0.5f * luv;  // WEIGHT = 0.5
    out[1] = lvu;
    out[2] = luv;
  }
}

extern "C" void kernel_launch(void* const* d_in, const int* in_sizes, int n_in,
                              void* d_out, int out_size, void* d_ws, size_t ws_size,
                              hipStream_t stream) {
  const float* img = (const float*)d_in[0];
  const float* txt = (const float*)d_in[1];
  float* out = (float*)d_out;
  const int N = in_sizes[0] / D_DIM;  // 16384

  char* ws = (char*)d_ws;
  __hip_bfloat16* Vb = (__hip_bfloat16*)ws;
  __hip_bfloat16* Ub = (__hip_bfloat16*)(ws + (size_t)N * D_DIM * 2);
  float* rowsum = (float*)(ws + (size_t)N * D_DIM * 4);
  float* colsum = rowsum + N;
  float* diagarr = colsum + N;
  float* acc3 = diagarr + N;

  normalize_kernel<<<N / 4, 256, 0, stream>>>(img, txt, Vb, Ub, diagarr,
                                              rowsum, acc3);

  const int nblocks = (N / BM) * (N / BN);  // 16384, 1-D grid for swizzle
  gemm_lse_kernel<<<nblocks, 256, 0, stream>>>(Vb, Ub, rowsum, colsum);

  finalize_partial<<<N / 256, 256, 0, stream>>>(rowsum, colsum, diagarr, acc3);
  finalize_combine<<<1, 64, 0, stream>>>(acc3, out, N);
}

// Round 7
// 322.155 us; speedup vs baseline: 2.0904x; 1.0785x over previous
//
#include <hip/hip_runtime.h>
#include <hip/hip_bf16.h>
#include <hip/hip_fp8.h>
#include <math.h>

// NT-Xent (CLIP) loss, N=16384 D=256 fp32 in, 3 fp32 out.
// loss_vu = mean_i( log(sum_j exp(sim_ij)) - sim_ii ), sim = (v̂·û^T)/T
// Logits bounded by 1/T=14.29 -> no max subtraction needed.
//
// R7: R2 shell (2-D grid, VGPR staging, __expf — the proven 235 µs shape)
//     with fp8-e4m3 operands. Pipe budget at R2 showed near-zero overlap:
//     LDS 91 + L2 61 + MFMA 66 + exp 14 ≈ 232 ≈ measured 235. fp8 halves
//     LDS and L2 bytes (staging/frags 1B/elt); mfma_f32_16x16x32_fp8_fp8
//     has identical fragment geometry to the bf16 16x16x32 (A: m=lane&15,
//     k=quad*8+j; C/D dtype-independent) so only dtypes/strides change.
//     Diag term stays fp32-exact; quantization error on the loss ~1e-3
//     vs threshold 0.2.

#define D_DIM 256
#define BM 128
#define BN 128
#define BK 64

constexpr float INV_T = 1.0f / 0.07f;

typedef float f32x4 __attribute__((ext_vector_type(4)));

// ---------------------------------------------------------------------------
// Kernel 1: L2-normalize (fp32 -> fp8 e4m3), one WAVE per row (4 rows/block).
//           Per-row diag contribution v̂_i·û_i (fp32, exact) to diagarr.
//           Blocks 0..127 zero rowsum/colsum; block 128 zeros acc3.
// ---------------------------------------------------------------------------
__global__ __launch_bounds__(256) void normalize_kernel(
    const float* __restrict__ img, const float* __restrict__ txt,
    unsigned char* __restrict__ Vb, unsigned char* __restrict__ Ub,
    float* __restrict__ diagarr, float* __restrict__ zero_region,
    float* __restrict__ acc3) {
  if (blockIdx.x < 128)
    zero_region[blockIdx.x * 256 + threadIdx.x] = 0.0f;
  else if (blockIdx.x == 128 && threadIdx.x < 4)
    acc3[threadIdx.x] = 0.0f;

  const int wave = threadIdx.x >> 6;
  const int lane = threadIdx.x & 63;
  const int row = blockIdx.x * 4 + wave;
  const size_t base = (size_t)row * D_DIM + lane * 4;

  const float4 iv = *reinterpret_cast<const float4*>(&img[base]);
  const float4 tv = *reinterpret_cast<const float4*>(&txt[base]);

  float a = iv.x * iv.x + iv.y * iv.y + iv.z * iv.z + iv.w * iv.w;
  float b = tv.x * tv.x + tv.y * tv.y + tv.z * tv.z + tv.w * tv.w;
#pragma unroll
  for (int off = 1; off < 64; off <<= 1) {
    a += __shfl_xor(a, off, 64);
    b += __shfl_xor(b, off, 64);
  }
  const float si = 1.0f / fmaxf(sqrtf(a), 1e-8f);
  const float st = 1.0f / fmaxf(sqrtf(b), 1e-8f);
  const float4 v = {iv.x * si, iv.y * si, iv.z * si, iv.w * si};
  const float4 u = {tv.x * st, tv.y * st, tv.z * st, tv.w * st};

  // fp8 e4m3 (OCP) pack: 4 bytes per lane -> coalesced 256B/row per wave.
  __hip_fp8_e4m3 qv0(v.x), qv1(v.y), qv2(v.z), qv3(v.w);
  __hip_fp8_e4m3 qu0(u.x), qu1(u.y), qu2(u.z), qu3(u.w);
  const unsigned int pv = (unsigned int)qv0.__x | ((unsigned int)qv1.__x << 8) |
                          ((unsigned int)qv2.__x << 16) | ((unsigned int)qv3.__x << 24);
  const unsigned int pu = (unsigned int)qu0.__x | ((unsigned int)qu1.__x << 8) |
                          ((unsigned int)qu2.__x << 16) | ((unsigned int)qu3.__x << 24);
  *reinterpret_cast<unsigned int*>(&Vb[base]) = pv;
  *reinterpret_cast<unsigned int*>(&Ub[base]) = pu;

  float d = v.x * u.x + v.y * u.y + v.z * u.z + v.w * u.w;  // exact diag
#pragma unroll
  for (int off = 1; off < 64; off <<= 1) d += __shfl_xor(d, off, 64);
  if (lane == 0) diagarr[row] = d;
}

// ---------------------------------------------------------------------------
// Kernel 2: fp8 MFMA GEMM over sim = V·U^T, online exp-sum per row/col.
// 128x128 tile/block, 4 waves of 64x64. Tiles are 128 rows x 64 B = 8 KB
// each (16 KB LDS total). Row = 4 x 16B chunks; chunk c8 of row r stored at
// pos c8 ^ (r&3) (swizzle keeps both staging writes and frag reads <=2
// lanes/bank, same algebra as R2's verified conflict-free layout).
// A-frag (16x16x32 fp8): A[m=lane&15][k=quad*8+j], 8 bytes (long).
// B symmetric (U row-major). C/D: col=lane&15, row=quad*4+reg.
// ---------------------------------------------------------------------------
__global__ __launch_bounds__(256) void gemm_lse_kernel(
    const unsigned char* __restrict__ V, const unsigned char* __restrict__ U,
    float* __restrict__ rowsum, float* __restrict__ colsum) {
  __shared__ __align__(16) unsigned char As[BM * BK];  // 8 KB
  __shared__ __align__(16) unsigned char Bs[BN * BK];  // 8 KB

  const int tid = threadIdx.x;
  const int lane = tid & 63;
  const int wave = tid >> 6;
  const int wm = wave >> 1;   // wave row (0..1)
  const int wn = wave & 1;    // wave col (0..1)
  const int quad = lane >> 4;
  const int l15 = lane & 15;
  const int ibase = blockIdx.y * BM;
  const int jbase = blockIdx.x * BN;

  f32x4 acc[4][4] = {};

  for (int kk = 0; kk < D_DIM; kk += BK) {
    // Stage A and B tiles: 512 x 16B chunks each; 2 chunks/thread each.
#pragma unroll
    for (int q = 0; q < 2; ++q) {
      const int chunk = q * 256 + tid;  // [0,512)
      const int row = chunk >> 2;       // 4 x 16B per 64-B row
      const int c8 = chunk & 3;
      const int dst = row * BK + ((c8 ^ (row & 3)) << 4);  // swizzled bytes
      const uint4 va = *reinterpret_cast<const uint4*>(
          &V[(size_t)(ibase + row) * D_DIM + kk + c8 * 16]);
      const uint4 vb = *reinterpret_cast<const uint4*>(
          &U[(size_t)(jbase + row) * D_DIM + kk + c8 * 16]);
      *reinterpret_cast<uint4*>(&As[dst]) = va;
      *reinterpret_cast<uint4*>(&Bs[dst]) = vb;
    }
    __syncthreads();

#pragma unroll
    for (int ks = 0; ks < BK; ks += 32) {
      // lane's 8 fp8 at k_local = ks + quad*8 + [0,8)
      const int chunkidx = (ks >> 4) + (quad >> 1);     // logical 16B chunk
      const int byte_in = (quad & 1) << 3;              // 0 or 8
      const int pcA = ((chunkidx ^ (l15 & 3)) << 4) + byte_in;
      long long af[4], bfr[4];
#pragma unroll
      for (int mi = 0; mi < 4; ++mi)
        af[mi] = *reinterpret_cast<const long long*>(
            &As[(wm * 64 + mi * 16 + l15) * BK + pcA]);
#pragma unroll
      for (int ni = 0; ni < 4; ++ni)
        bfr[ni] = *reinterpret_cast<const long long*>(
            &Bs[(wn * 64 + ni * 16 + l15) * BK + pcA]);
#pragma unroll
      for (int mi = 0; mi < 4; ++mi)
#pragma unroll
        for (int ni = 0; ni < 4; ++ni)
          acc[mi][ni] = __builtin_amdgcn_mfma_f32_16x16x32_fp8_fp8(
              af[mi], bfr[ni], acc[mi][ni], 0, 0, 0);
    }
    __syncthreads();
  }

  // ---- epilogue: exp + row/col reduction ----
  // acc[mi][ni][r]: row = wm*64+mi*16+quad*4+r, col = wn*64+ni*16+l15.
#pragma unroll
  for (int mi = 0; mi < 4; ++mi)
#pragma unroll
    for (int ni = 0; ni < 4; ++ni)
#pragma unroll
      for (int r = 0; r < 4; ++r)
        acc[mi][ni][r] = __expf(acc[mi][ni][r] * INV_T);

  // Reuse As as fp32 scratch: rowbuf[128], colbuf[128].
  float* rowbuf = reinterpret_cast<float*>(As);
  float* colbuf = rowbuf + BM;
  reinterpret_cast<float*>(As)[tid] = 0.0f;  // zero 256 floats
  __syncthreads();

  // Row sums: reduce across 16 cols, two wn halves meet in LDS.
#pragma unroll
  for (int mi = 0; mi < 4; ++mi) {
#pragma unroll
    for (int r = 0; r < 4; ++r) {
      float rs = acc[mi][0][r] + acc[mi][1][r] + acc[mi][2][r] + acc[mi][3][r];
      rs += __shfl_xor(rs, 1, 64);
      rs += __shfl_xor(rs, 2, 64);
      rs += __shfl_xor(rs, 4, 64);
      rs += __shfl_xor(rs, 8, 64);
      if (l15 == 0)
        atomicAdd(&rowbuf[wm * 64 + mi * 16 + quad * 4 + r], rs);
    }
  }
  // Col sums: reduce across 16 rows (quads), two wm halves meet in LDS.
#pragma unroll
  for (int ni = 0; ni < 4; ++ni) {
    float cs = 0.0f;
#pragma unroll
    for (int mi = 0; mi < 4; ++mi)
      cs += acc[mi][ni][0] + acc[mi][ni][1] + acc[mi][ni][2] + acc[mi][ni][3];
    cs += __shfl_xor(cs, 16, 64);
    cs += __shfl_xor(cs, 32, 64);
    if (lane < 16)
      atomicAdd(&colbuf[wn * 64 + ni * 16 + l15], cs);
  }
  __syncthreads();

  if (tid < BM)
    atomicAdd(&rowsum[ibase + tid], rowbuf[tid]);
  else
    atomicAdd(&colsum[jbase + tid - BM], colbuf[tid - BM]);
}

// ---------------------------------------------------------------------------
// Kernel 3a: parallel partial finalize — block-reduce; one atomicAdd per
//            block into acc3[3].
// ---------------------------------------------------------------------------
__global__ __launch_bounds__(256) void finalize_partial(
    const float* __restrict__ rowsum, const float* __restrict__ colsum,
    const float* __restrict__ diagarr, float* __restrict__ acc3) {
  const int idx = blockIdx.x * 256 + threadIdx.x;
  float sr = logf(rowsum[idx]);
  float sc = logf(colsum[idx]);
  float sd = diagarr[idx];
#pragma unroll
  for (int off = 1; off < 64; off <<= 1) {
    sr += __shfl_xor(sr, off, 64);
    sc += __shfl_xor(sc, off, 64);
    sd += __shfl_xor(sd, off, 64);
  }
  __shared__ float sh[12];
  const int w = threadIdx.x >> 6, lane = threadIdx.x & 63;
  if (lane == 0) { sh[w] = sr; sh[4 + w] = sc; sh[8 + w] = sd; }
  __syncthreads();
  if (threadIdx.x == 0) {
    atomicAdd(&acc3[0], sh[0] + sh[1] + sh[2] + sh[3]);
    atomicAdd(&acc3[1], sh[4] + sh[5] + sh[6] + sh[7]);
    atomicAdd(&acc3[2], sh[8] + sh[9] + sh[10] + sh[11]);
  }
}

// ---------------------------------------------------------------------------
// Kernel 3b: combine.
// ---------------------------------------------------------------------------
__global__ __launch_bounds__(64) void finalize_combine(
    const float* __restrict__ acc3, float* __restrict__ out, int n) {
  if (threadIdx.x == 0) {
    const float invN = 1.0f / (float)n;
    const float dm = acc3[2] * INV_T * invN;   // mean diag logit
    const float lvu = acc3[0] * invN - dm;
    const float luv = acc3[1] * invN - dm;
    out[0] = 0.5f * lvu + 0.5f * luv;  // WEIGHT = 0.5
    out[1] = lvu;
    out[2] = luv;
  }
}

extern "C" void kernel_launch(void* const* d_in, const int* in_sizes, int n_in,
                              void* d_out, int out_size, void* d_ws, size_t ws_size,
                              hipStream_t stream) {
  const float* img = (const float*)d_in[0];
  const float* txt = (const float*)d_in[1];
  float* out = (float*)d_out;
  const int N = in_sizes[0] / D_DIM;  // 16384

  char* ws = (char*)d_ws;
  unsigned char* Vb = (unsigned char*)ws;
  unsigned char* Ub = (unsigned char*)(ws + (size_t)N * D_DIM);
  float* rowsum = (float*)(ws + (size_t)N * D_DIM * 2);
  float* colsum = rowsum + N;
  float* diagarr = colsum + N;
  float* acc3 = diagarr + N;

  normalize_kernel<<<N / 4, 256, 0, stream>>>(img, txt, Vb, Ub, diagarr,
                                              rowsum, acc3);

  dim3 grid(N / BN, N / BM);
  gemm_lse_kernel<<<grid, 256, 0, stream>>>(Vb, Ub, rowsum, colsum);

  finalize_partial<<<N / 256, 256, 0, stream>>>(rowsum, colsum, diagarr, acc3);
  finalize_combine<<<1, 64, 0, stream>>>(acc3, out, N);
}